// Round 1
// baseline (714.015 us; speedup 1.0000x reference)
//
#include <hip/hip_runtime.h>

// Problem constants
#define NTOK 343   // tokens per window (7*7*7)
#define NPAD 352   // 22 * 16
#define CEMB 192
#define NH   6
#define HD   32
#define NB   256
#define NWIN 64

typedef __attribute__((ext_vector_type(8))) short short8;   // 8 x bf16 bits
typedef __attribute__((ext_vector_type(4))) float f32x4;

__device__ __forceinline__ unsigned short f2bf(float f) {
    unsigned int u = __builtin_bit_cast(unsigned int, f);
    u += 0x7fffu + ((u >> 16) & 1u);          // round-to-nearest-even
    return (unsigned short)(u >> 16);
}
__device__ __forceinline__ float bf2f(unsigned short h) {
    unsigned int u = ((unsigned int)h) << 16;
    return __builtin_bit_cast(float, u);
}

// ---------------- prep: weights -> bf16 ----------------
__global__ void prep_weights(const float* __restrict__ qw, const float* __restrict__ kvw,
                             const float* __restrict__ pw,
                             unsigned short* __restrict__ qwb, unsigned short* __restrict__ kvwb,
                             unsigned short* __restrict__ pwb) {
    int idx = blockIdx.x * 256 + threadIdx.x;
    if (idx < 36864)        qwb[idx] = f2bf(qw[idx]);
    else if (idx < 110592)  kvwb[idx - 36864] = f2bf(kvw[idx - 36864]);
    else if (idx < 147456)  pwb[idx - 110592] = f2bf(pw[idx - 110592]);
}

// ---------------- prep: biasT[h][key][q] (bf16, padded to 352x352) ----------------
__global__ void prep_biasT(const float* __restrict__ table, const int* __restrict__ rel,
                           unsigned short* __restrict__ biasT) {
    __shared__ int sidx[32 * 33];
    int bid = blockIdx.x;                  // 121 blocks: kt*11 + qt
    int kt = bid / 11, qt = bid - kt * 11;
    int k0 = kt * 32, q0 = qt * 32;
    for (int e = threadIdx.x; e < 1024; e += 256) {
        int i = e >> 5, j = e & 31;        // i: q-local, j: key-local
        int q = q0 + i, k = k0 + j;
        sidx[i * 33 + j] = (q < NTOK && k < NTOK) ? rel[q * NTOK + k] : -1;
    }
    __syncthreads();
    for (int h = 0; h < NH; h++) {
        for (int e = threadIdx.x; e < 1024; e += 256) {
            int kk = e >> 5, qq = e & 31;
            int idx = sidx[qq * 33 + kk];
            float v = (idx >= 0) ? table[idx * NH + h] : 0.f;
            biasT[((size_t)h * NPAD + (k0 + kk)) * NPAD + (q0 + qq)] = f2bf(v);
        }
    }
}

// ---------------- prep: maskT[w][key][q] (bf16, padded) ----------------
__global__ void prep_maskT(const float* __restrict__ mask, unsigned short* __restrict__ maskT) {
    __shared__ float sm[32 * 33];
    int bid = blockIdx.x;                  // 64*121 blocks
    int w = bid / 121;
    int rem = bid - w * 121;
    int kt = rem / 11, qt = rem - kt * 11;
    int k0 = kt * 32, q0 = qt * 32;
    for (int e = threadIdx.x; e < 1024; e += 256) {
        int i = e >> 5, j = e & 31;        // i: q-local, j: key-local
        int q = q0 + i, k = k0 + j;
        sm[i * 33 + j] = (q < NTOK && k < NTOK) ? mask[((size_t)w * NTOK + q) * NTOK + k] : 0.f;
    }
    __syncthreads();
    for (int e = threadIdx.x; e < 1024; e += 256) {
        int kk = e >> 5, qq = e & 31;
        maskT[((size_t)w * NPAD + (k0 + kk)) * NPAD + (q0 + qq)] = f2bf(sm[qq * 33 + kk]);
    }
}

// ---------------- fused attention per (window b, head h) ----------------
// LDS map (dynamic, 143360 B total):
//   Ks  [352][40] bf16 @ 0       (28160)  K rows, B-frag layout
//   Vt  [32][360] bf16 @ 28160   (23040)  V transposed (d-major), B-frag layout for PV
//   area @ 51200 (92160):
//     phase A: Xc[352][40] @ +0, Xi[352][40] @ +28160, Qs[352][40] @ +56320
//     phase B: per-wave P strip [16][360] bf16 @ + wave*11520
__global__ __launch_bounds__(512, 2)
void attn_kernel(const float* __restrict__ x_in, const float* __restrict__ x_cross,
                 const unsigned short* __restrict__ qwb, const unsigned short* __restrict__ kvwb,
                 const unsigned short* __restrict__ biasT, const unsigned short* __restrict__ maskT,
                 unsigned short* __restrict__ attnb) {
    extern __shared__ char smem[];
    unsigned short* Ks = (unsigned short*)smem;
    unsigned short* Vt = (unsigned short*)(smem + 28160);
    char* area = smem + 51200;

    const int tid = threadIdx.x;
    const int wave = tid >> 6, lane = tid & 63;
    const int quad = lane >> 4, l16 = lane & 15;
    const int bx = blockIdx.x;
    const int b = bx / NH, h = bx - b * NH;

    unsigned short* Xc = (unsigned short*)area;
    unsigned short* Xi = (unsigned short*)(area + 28160);
    unsigned short* Qs = (unsigned short*)(area + 56320);

    const f32x4 zero4 = {0.f, 0.f, 0.f, 0.f};
    f32x4 kacc[6], vacc[6], qacc[6];
#pragma unroll
    for (int t = 0; t < 6; t++) { kacc[t] = zero4; vacc[t] = zero4; qacc[t] = zero4; }

    // ---- Phase A: project Q,K,V (K over 6 chunks of 32 of CEMB) ----
    for (int kc = 0; kc < 6; kc++) {
        // stage x_cross -> Xc and x_in -> Xi (bf16, rows >= NTOK zeroed)
        for (int idx = tid; idx < 2816 * 2; idx += 512) {
            int which = idx >= 2816;
            int e = which ? idx - 2816 : idx;
            int n = e >> 3, c4 = (e & 7) << 2;
            float4 v = {0.f, 0.f, 0.f, 0.f};
            if (n < NTOK) {
                const float* src = which ? x_in : x_cross;
                v = *(const float4*)(src + ((size_t)b * NTOK + n) * CEMB + kc * 32 + c4);
            }
            unsigned short* dst = which ? Xi : Xc;
            ushort4 pk;
            pk.x = f2bf(v.x); pk.y = f2bf(v.y); pk.z = f2bf(v.z); pk.w = f2bf(v.w);
            *(ushort4*)(dst + n * 40 + c4) = pk;
        }
        __syncthreads();
#pragma unroll
        for (int t = 0; t < 6; t++) {
            int id = wave + (t << 3);          // job id: 44 (mt,nt) jobs, each does K,V,Q
            if (id < 44) {
                int mt = id >> 1, nt = id & 1;
                const short8 aKV = *(const short8*)(Xc + (mt * 16 + l16) * 40 + (quad << 3));
                const unsigned short* wrow =
                    kvwb + ((size_t)(h * 32 + nt * 16 + l16)) * CEMB + kc * 32 + (quad << 3);
                const short8 bK = *(const short8*)(wrow);
                const short8 bV = *(const short8*)(wrow + 192 * CEMB);
                kacc[t] = __builtin_amdgcn_mfma_f32_16x16x32_bf16(aKV, bK, kacc[t], 0, 0, 0);
                vacc[t] = __builtin_amdgcn_mfma_f32_16x16x32_bf16(aKV, bV, vacc[t], 0, 0, 0);
                const short8 aQ = *(const short8*)(Xi + (mt * 16 + l16) * 40 + (quad << 3));
                const short8 bQ = *(const short8*)(
                    qwb + ((size_t)(h * 32 + nt * 16 + l16)) * CEMB + kc * 32 + (quad << 3));
                qacc[t] = __builtin_amdgcn_mfma_f32_16x16x32_bf16(aQ, bQ, qacc[t], 0, 0, 0);
            }
        }
        __syncthreads();
    }
    // write K, V, Q into their LDS layouts (pad rows are zeros automatically)
    const float scale = 0.17677669529663689f;   // 32^-0.5, folded into Q
#pragma unroll
    for (int t = 0; t < 6; t++) {
        int id = wave + (t << 3);
        if (id < 44) {
            int mt = id >> 1, nt = id & 1;
#pragma unroll
            for (int r = 0; r < 4; r++) {
                int m = mt * 16 + (quad << 2) + r;   // token index
                int d = nt * 16 + l16;               // channel
                Ks[m * 40 + d] = f2bf(kacc[t][r]);
                Vt[d * 360 + m] = f2bf(vacc[t][r]);
                Qs[m * 40 + d] = f2bf(qacc[t][r] * scale);
            }
        }
    }
    __syncthreads();
    // preload this wave's Q A-frags (then Qs area is recycled as P strips)
    short8 qa[3] = {};
#pragma unroll
    for (int i = 0; i < 3; i++) {
        int mt = wave + (i << 3);
        if (mt < 22) qa[i] = *(const short8*)(Qs + (mt * 16 + l16) * 40 + (quad << 3));
    }
    __syncthreads();

    // ---- Phase B: per-wave M-tiles, S -> softmax -> PV ----
    unsigned short* P = (unsigned short*)(area + wave * 11520);   // [16][360]
    const unsigned short* biasTp = biasT + (size_t)h * NPAD * NPAD;
    const unsigned short* maskTp = maskT + (size_t)(b & 63) * NPAD * NPAD;
#pragma unroll
    for (int i = 0; i < 3; i++) {
        int mt = wave + (i << 3);
        if (mt >= 22) continue;              // wave-uniform, no barriers below
        int q0 = mt * 16 + (quad << 2);      // global q row of C-frag elems
        float rp[4] = {0.f, 0.f, 0.f, 0.f};
        for (int kt = 0; kt < 22; kt++) {
            int key = kt * 16 + l16;
            const short8 kb = *(const short8*)(Ks + key * 40 + (quad << 3));
            f32x4 s = __builtin_amdgcn_mfma_f32_16x16x32_bf16(qa[i], kb, zero4, 0, 0, 0);
            ushort4 bt = *(const ushort4*)(biasTp + (size_t)key * NPAD + q0);
            ushort4 mk = *(const ushort4*)(maskTp + (size_t)key * NPAD + q0);
            float p0 = __expf(s[0] + bf2f(bt.x) + bf2f(mk.x));
            float p1 = __expf(s[1] + bf2f(bt.y) + bf2f(mk.y));
            float p2 = __expf(s[2] + bf2f(bt.z) + bf2f(mk.z));
            float p3 = __expf(s[3] + bf2f(bt.w) + bf2f(mk.w));
            if (key >= NTOK) { p0 = 0.f; p1 = 0.f; p2 = 0.f; p3 = 0.f; }  // pad keys
            rp[0] += p0; rp[1] += p1; rp[2] += p2; rp[3] += p3;
            unsigned short* pw = P + kt * 16 + l16;
            pw[((quad << 2) + 0) * 360] = f2bf(p0);
            pw[((quad << 2) + 1) * 360] = f2bf(p1);
            pw[((quad << 2) + 2) * 360] = f2bf(p2);
            pw[((quad << 2) + 3) * 360] = f2bf(p3);
        }
        // reduce row sums across the 16 col-lanes (xor bits 0..3 stay in-quad)
#pragma unroll
        for (int mm = 1; mm <= 8; mm <<= 1) {
            rp[0] += __shfl_xor(rp[0], mm);
            rp[1] += __shfl_xor(rp[1], mm);
            rp[2] += __shfl_xor(rp[2], mm);
            rp[3] += __shfl_xor(rp[3], mm);
        }
        f32x4 o0 = zero4, o1 = zero4;
#pragma unroll
        for (int ks = 0; ks < 11; ks++) {
            const short8 pa = *(const short8*)(P + l16 * 360 + ks * 32 + (quad << 3));
            const short8 v0 = *(const short8*)(Vt + l16 * 360 + ks * 32 + (quad << 3));
            const short8 v1 = *(const short8*)(Vt + (16 + l16) * 360 + ks * 32 + (quad << 3));
            o0 = __builtin_amdgcn_mfma_f32_16x16x32_bf16(pa, v0, o0, 0, 0, 0);
            o1 = __builtin_amdgcn_mfma_f32_16x16x32_bf16(pa, v1, o1, 0, 0, 0);
        }
#pragma unroll
        for (int r = 0; r < 4; r++) {
            int n = mt * 16 + (quad << 2) + r;
            if (n < NTOK) {
                float inv = 1.f / rp[r];
                size_t base = ((size_t)b * NTOK + n) * CEMB + h * 32;
                attnb[base + l16] = f2bf(o0[r] * inv);
                attnb[base + 16 + l16] = f2bf(o1[r] * inv);
            }
        }
    }
}

// ---------------- output projection: out = attn @ proj_w^T + proj_b ----------------
__global__ __launch_bounds__(256, 4)
void proj_kernel(const unsigned short* __restrict__ attnb, const unsigned short* __restrict__ pwb,
                 const float* __restrict__ proj_b, float* __restrict__ out) {
    const int tid = threadIdx.x;
    const int wave = tid >> 6, lane = tid & 63;
    const int quad = lane >> 4, l16 = lane & 15;
    const int mt = blockIdx.x * 4 + wave;   // 5488 M-tiles total, exact
    const f32x4 zero4 = {0.f, 0.f, 0.f, 0.f};
    f32x4 acc[12];
#pragma unroll
    for (int nt = 0; nt < 12; nt++) acc[nt] = zero4;
#pragma unroll
    for (int ks = 0; ks < 6; ks++) {
        const short8 a = *(const short8*)(attnb + ((size_t)mt * 16 + l16) * CEMB + ks * 32 + (quad << 3));
#pragma unroll
        for (int nt = 0; nt < 12; nt++) {
            const short8 bfrag = *(const short8*)(pwb + ((size_t)(nt * 16 + l16)) * CEMB + ks * 32 + (quad << 3));
            acc[nt] = __builtin_amdgcn_mfma_f32_16x16x32_bf16(a, bfrag, acc[nt], 0, 0, 0);
        }
    }
#pragma unroll
    for (int nt = 0; nt < 12; nt++) {
        float bias = proj_b[nt * 16 + l16];
#pragma unroll
        for (int r = 0; r < 4; r++) {
            int m = mt * 16 + (quad << 2) + r;
            out[(size_t)m * CEMB + nt * 16 + l16] = acc[nt][r] + bias;
        }
    }
}

// ---------------- launch ----------------
extern "C" void kernel_launch(void* const* d_in, const int* in_sizes, int n_in,
                              void* d_out, int out_size, void* d_ws, size_t ws_size,
                              hipStream_t stream) {
    (void)in_sizes; (void)n_in; (void)out_size; (void)ws_size;
    const float* x_in    = (const float*)d_in[0];
    const float* x_cross = (const float*)d_in[1];
    const float* mask    = (const float*)d_in[2];
    const float* q_w     = (const float*)d_in[3];
    const float* kv_w    = (const float*)d_in[4];
    const float* proj_w  = (const float*)d_in[5];
    const float* proj_b  = (const float*)d_in[6];
    const float* btab    = (const float*)d_in[7];
    const int*   rel     = (const int*)d_in[8];
    float* out = (float*)d_out;
    char* ws = (char*)d_ws;

    // ws layout (bytes): 51,359,744 total
    unsigned short* qwb   = (unsigned short*)(ws + 0);         //    73,728
    unsigned short* kvwb  = (unsigned short*)(ws + 73728);     //   147,456
    unsigned short* pwb   = (unsigned short*)(ws + 221184);    //    73,728
    unsigned short* biasT = (unsigned short*)(ws + 294912);    // 1,486,848
    unsigned short* maskT = (unsigned short*)(ws + 1781760);   // 15,859,712
    unsigned short* attnb = (unsigned short*)(ws + 17641472);  // 33,718,272

    hipFuncSetAttribute(reinterpret_cast<const void*>(attn_kernel),
                        hipFuncAttributeMaxDynamicSharedMemorySize, 143360);

    prep_weights<<<576, 256, 0, stream>>>(q_w, kv_w, proj_w, qwb, kvwb, pwb);
    prep_biasT<<<121, 256, 0, stream>>>(btab, rel, biasT);
    prep_maskT<<<64 * 121, 256, 0, stream>>>(mask, maskT);
    attn_kernel<<<NB * NH, 512, 143360, stream>>>(x_in, x_cross, qwb, kvwb, biasT, maskT, attnb);
    proj_kernel<<<5488 / 4, 256, 0, stream>>>(attnb, pwb, proj_b, out);
}

// Round 2
// 588.603 us; speedup vs baseline: 1.2131x; 1.2131x over previous
//
#include <hip/hip_runtime.h>

// Problem constants
#define NTOK 343   // tokens per window (7*7*7)
#define NPAD 352   // 22 * 16
#define CEMB 192
#define NH   6
#define HD   32
#define NB   256
#define NWIN 64

typedef __attribute__((ext_vector_type(8))) short short8;   // 8 x bf16 bits
typedef __attribute__((ext_vector_type(4))) float f32x4;

__device__ __forceinline__ unsigned short f2bf(float f) {
    unsigned int u = __builtin_bit_cast(unsigned int, f);
    u += 0x7fffu + ((u >> 16) & 1u);          // round-to-nearest-even
    return (unsigned short)(u >> 16);
}
__device__ __forceinline__ float bf2f(unsigned short h) {
    unsigned int u = ((unsigned int)h) << 16;
    return __builtin_bit_cast(float, u);
}
__device__ __forceinline__ short8 pack8(float4 f0, float4 f1) {
    short8 r;
    r[0] = (short)f2bf(f0.x); r[1] = (short)f2bf(f0.y);
    r[2] = (short)f2bf(f0.z); r[3] = (short)f2bf(f0.w);
    r[4] = (short)f2bf(f1.x); r[5] = (short)f2bf(f1.y);
    r[6] = (short)f2bf(f1.z); r[7] = (short)f2bf(f1.w);
    return r;
}

// ---------------- prep: weights -> bf16 (scale folded into qw) ----------------
__global__ void prep_weights(const float* __restrict__ qw, const float* __restrict__ kvw,
                             const float* __restrict__ pw,
                             unsigned short* __restrict__ qwb, unsigned short* __restrict__ kvwb,
                             unsigned short* __restrict__ pwb) {
    const float scale = 0.17677669529663689f;   // 32^-0.5 folded into Q weights
    int idx = blockIdx.x * 256 + threadIdx.x;
    if (idx < 36864)        qwb[idx] = f2bf(qw[idx] * scale);
    else if (idx < 110592)  kvwb[idx - 36864] = f2bf(kvw[idx - 36864]);
    else if (idx < 147456)  pwb[idx - 110592] = f2bf(pw[idx - 110592]);
}

// ---------------- prep: biasT[h][key][q] (bf16, padded to 352x352) ----------------
__global__ void prep_biasT(const float* __restrict__ table, const int* __restrict__ rel,
                           unsigned short* __restrict__ biasT) {
    __shared__ int sidx[32 * 33];
    int bid = blockIdx.x;                  // 121 blocks: kt*11 + qt
    int kt = bid / 11, qt = bid - kt * 11;
    int k0 = kt * 32, q0 = qt * 32;
    for (int e = threadIdx.x; e < 1024; e += 256) {
        int i = e >> 5, j = e & 31;        // i: q-local, j: key-local
        int q = q0 + i, k = k0 + j;
        sidx[i * 33 + j] = (q < NTOK && k < NTOK) ? rel[q * NTOK + k] : -1;
    }
    __syncthreads();
    for (int h = 0; h < NH; h++) {
        for (int e = threadIdx.x; e < 1024; e += 256) {
            int kk = e >> 5, qq = e & 31;
            int idx = sidx[qq * 33 + kk];
            float v = (idx >= 0) ? table[idx * NH + h] : 0.f;
            biasT[((size_t)h * NPAD + (k0 + kk)) * NPAD + (q0 + qq)] = f2bf(v);
        }
    }
}

// ---------------- prep: maskT[w][key][q] (bf16, padded) ----------------
__global__ void prep_maskT(const float* __restrict__ mask, unsigned short* __restrict__ maskT) {
    __shared__ float sm[32 * 33];
    int bid = blockIdx.x;                  // 64*121 blocks
    int w = bid / 121;
    int rem = bid - w * 121;
    int kt = rem / 11, qt = rem - kt * 11;
    int k0 = kt * 32, q0 = qt * 32;
    for (int e = threadIdx.x; e < 1024; e += 256) {
        int i = e >> 5, j = e & 31;        // i: q-local, j: key-local
        int q = q0 + i, k = k0 + j;
        sm[i * 33 + j] = (q < NTOK && k < NTOK) ? mask[((size_t)w * NTOK + q) * NTOK + k] : 0.f;
    }
    __syncthreads();
    for (int e = threadIdx.x; e < 1024; e += 256) {
        int kk = e >> 5, qq = e & 31;
        maskT[((size_t)w * NPAD + (k0 + kk)) * NPAD + (q0 + qq)] = f2bf(sm[qq * 33 + kk]);
    }
}

// ---------------- QKV projection GEMM ----------------
// One block per (b, o) with o in {Q, K, V}. No LDS; A from global fp32,
// B (bf16 weights) from global (L2-resident), acc in regs.
// Outputs: Qb[b][352][192] (scaled via weights), Kb[b][352][192],
//          Vtb[b][h][d 32][m 360] (transposed for PV B-frags).
__global__ __launch_bounds__(512, 2)
void qkv_kernel(const float* __restrict__ x_in, const float* __restrict__ x_cross,
                const unsigned short* __restrict__ qwb, const unsigned short* __restrict__ kvwb,
                unsigned short* __restrict__ Qb, unsigned short* __restrict__ Kb,
                unsigned short* __restrict__ Vtb) {
    const int tid = threadIdx.x;
    const int wave = tid >> 6, lane = tid & 63;
    const int quad = lane >> 4, l16 = lane & 15;
    const int b = blockIdx.x / 3, o = blockIdx.x % 3;
    const float* xsrc = (o == 0) ? x_in : x_cross;
    const unsigned short* wsrc = (o == 0) ? qwb : (o == 1 ? kvwb : (kvwb + 192 * CEMB));
    const f32x4 zero4 = {0.f, 0.f, 0.f, 0.f};

    for (int mi = 0; mi < 3; mi++) {
        int mt = wave + (mi << 3);
        if (mt >= 22) continue;            // wave-uniform
        int row = mt * 16 + l16;
        f32x4 acc[12];
#pragma unroll
        for (int nt = 0; nt < 12; nt++) acc[nt] = zero4;
#pragma unroll
        for (int kc = 0; kc < 6; kc++) {
            short8 a = {};
            if (row < NTOK) {
                const float* xp = xsrc + ((size_t)b * NTOK + row) * CEMB + kc * 32 + (quad << 3);
                float4 f0 = *(const float4*)xp;
                float4 f1 = *(const float4*)(xp + 4);
                a = pack8(f0, f1);
            }
#pragma unroll
            for (int nt = 0; nt < 12; nt++) {
                const short8 bf = *(const short8*)(wsrc + ((size_t)(nt * 16 + l16)) * CEMB + kc * 32 + (quad << 3));
                acc[nt] = __builtin_amdgcn_mfma_f32_16x16x32_bf16(a, bf, acc[nt], 0, 0, 0);
            }
        }
        if (o < 2) {
            unsigned short* dst = (o == 0 ? Qb : Kb) + (size_t)b * NPAD * CEMB;
#pragma unroll
            for (int nt = 0; nt < 12; nt++) {
#pragma unroll
                for (int r = 0; r < 4; r++) {
                    int m = mt * 16 + (quad << 2) + r;
                    dst[(size_t)m * CEMB + nt * 16 + l16] = f2bf(acc[nt][r]);
                }
            }
        } else {
#pragma unroll
            for (int nt = 0; nt < 12; nt++) {
                int h = nt >> 1, d = ((nt & 1) << 4) + l16;
#pragma unroll
                for (int r = 0; r < 4; r++) {
                    int m = mt * 16 + (quad << 2) + r;
                    Vtb[(((size_t)b * NH + h) * 32 + d) * 360 + m] = f2bf(acc[nt][r]);
                }
            }
        }
    }
}

// ---------------- fused attention per (window b, head h) ----------------
// LDS (dynamic, 63488 B): Ks[352][40] @0 (28160), Vt[32][360] @28160 (23040),
// P strips 8 x [16][48] @51200 (12288). 2 blocks/CU.
// Streaming PV: per 32-key chunk, 2 S-MFMAs -> exp -> P strip -> 2 PV MFMAs.
__global__ __launch_bounds__(512, 4)
void attn_kernel(const unsigned short* __restrict__ Qb, const unsigned short* __restrict__ Kb,
                 const unsigned short* __restrict__ Vtb,
                 const unsigned short* __restrict__ biasT, const unsigned short* __restrict__ maskT,
                 unsigned short* __restrict__ attnb) {
    extern __shared__ char smem[];
    unsigned short* Ks = (unsigned short*)smem;             // [352][40]
    unsigned short* Vt = (unsigned short*)(smem + 28160);   // [32][360]
    unsigned short* Pb = (unsigned short*)(smem + 51200);   // 8 x [16][48]

    const int tid = threadIdx.x;
    const int wave = tid >> 6, lane = tid & 63;
    const int quad = lane >> 4, l16 = lane & 15;
    const int b = blockIdx.x / NH, h = blockIdx.x - (blockIdx.x / NH) * NH;
    const f32x4 zero4 = {0.f, 0.f, 0.f, 0.f};

    // stage K (this head's 32 channels) into B-frag layout [key][40]
    for (int i = tid; i < 1408; i += 512) {
        int key = i >> 2, part = i & 3;
        *(short8*)(Ks + key * 40 + part * 8) =
            *(const short8*)(Kb + ((size_t)b * NPAD + key) * CEMB + h * 32 + part * 8);
    }
    // stage V^T (contiguous copy of this (b,h) plane)
    const unsigned short* vsrc = Vtb + (size_t)(b * NH + h) * 32 * 360;
    for (int i = tid; i < 1440; i += 512) {
        *(short8*)(Vt + i * 8) = *(const short8*)(vsrc + i * 8);
    }
    // per-wave Q A-frags straight from global
    short8 qa[3] = {};
#pragma unroll
    for (int i = 0; i < 3; i++) {
        int mt = wave + (i << 3);
        if (mt < 22)
            qa[i] = *(const short8*)(Qb + ((size_t)b * NPAD + mt * 16 + l16) * CEMB + h * 32 + (quad << 3));
    }
    __syncthreads();

    unsigned short* P = Pb + wave * 768;    // [16][48]
    const unsigned short* biasTp = biasT + (size_t)h * NPAD * NPAD;
    const unsigned short* maskTp = maskT + (size_t)(b & 63) * NPAD * NPAD;
#pragma unroll
    for (int i = 0; i < 3; i++) {
        int mt = wave + (i << 3);
        if (mt >= 22) continue;             // wave-uniform, no barriers below
        const int q0 = mt * 16 + (quad << 2);
        float rp[4] = {0.f, 0.f, 0.f, 0.f};
        f32x4 o0 = zero4, o1 = zero4;
        for (int ch = 0; ch < 11; ch++) {
#pragma unroll
            for (int t = 0; t < 2; t++) {
                int key = ch * 32 + t * 16 + l16;
                const short8 kb = *(const short8*)(Ks + key * 40 + (quad << 3));
                f32x4 s = __builtin_amdgcn_mfma_f32_16x16x32_bf16(qa[i], kb, zero4, 0, 0, 0);
                ushort4 bt = *(const ushort4*)(biasTp + (size_t)key * NPAD + q0);
                ushort4 mk = *(const ushort4*)(maskTp + (size_t)key * NPAD + q0);
                float p0 = __expf(s[0] + bf2f(bt.x) + bf2f(mk.x));
                float p1 = __expf(s[1] + bf2f(bt.y) + bf2f(mk.y));
                float p2 = __expf(s[2] + bf2f(bt.z) + bf2f(mk.z));
                float p3 = __expf(s[3] + bf2f(bt.w) + bf2f(mk.w));
                if (key >= NTOK) { p0 = 0.f; p1 = 0.f; p2 = 0.f; p3 = 0.f; }  // pad keys
                rp[0] += p0; rp[1] += p1; rp[2] += p2; rp[3] += p3;
                unsigned short* pw = P + t * 16 + l16;
                pw[((quad << 2) + 0) * 48] = f2bf(p0);
                pw[((quad << 2) + 1) * 48] = f2bf(p1);
                pw[((quad << 2) + 2) * 48] = f2bf(p2);
                pw[((quad << 2) + 3) * 48] = f2bf(p3);
            }
            const short8 pa = *(const short8*)(P + l16 * 48 + (quad << 3));
            const short8 v0 = *(const short8*)(Vt + l16 * 360 + ch * 32 + (quad << 3));
            const short8 v1 = *(const short8*)(Vt + (16 + l16) * 360 + ch * 32 + (quad << 3));
            o0 = __builtin_amdgcn_mfma_f32_16x16x32_bf16(pa, v0, o0, 0, 0, 0);
            o1 = __builtin_amdgcn_mfma_f32_16x16x32_bf16(pa, v1, o1, 0, 0, 0);
        }
        // reduce row sums across the 16 col-lanes (xor bits 0..3 stay in-quad)
#pragma unroll
        for (int mm = 1; mm <= 8; mm <<= 1) {
            rp[0] += __shfl_xor(rp[0], mm);
            rp[1] += __shfl_xor(rp[1], mm);
            rp[2] += __shfl_xor(rp[2], mm);
            rp[3] += __shfl_xor(rp[3], mm);
        }
#pragma unroll
        for (int r = 0; r < 4; r++) {
            int n = mt * 16 + (quad << 2) + r;
            if (n < NTOK) {
                float inv = 1.f / rp[r];
                size_t base = ((size_t)b * NTOK + n) * CEMB + h * 32;
                attnb[base + l16] = f2bf(o0[r] * inv);
                attnb[base + 16 + l16] = f2bf(o1[r] * inv);
            }
        }
    }
}

// ---------------- output projection: out = attn @ proj_w^T + proj_b ----------------
__global__ __launch_bounds__(256, 4)
void proj_kernel(const unsigned short* __restrict__ attnb, const unsigned short* __restrict__ pwb,
                 const float* __restrict__ proj_b, float* __restrict__ out) {
    const int tid = threadIdx.x;
    const int wave = tid >> 6, lane = tid & 63;
    const int quad = lane >> 4, l16 = lane & 15;
    const int mt = blockIdx.x * 4 + wave;   // 5488 M-tiles total, exact
    const f32x4 zero4 = {0.f, 0.f, 0.f, 0.f};
    f32x4 acc[12];
#pragma unroll
    for (int nt = 0; nt < 12; nt++) acc[nt] = zero4;
#pragma unroll
    for (int ks = 0; ks < 6; ks++) {
        const short8 a = *(const short8*)(attnb + ((size_t)mt * 16 + l16) * CEMB + ks * 32 + (quad << 3));
#pragma unroll
        for (int nt = 0; nt < 12; nt++) {
            const short8 bfrag = *(const short8*)(pwb + ((size_t)(nt * 16 + l16)) * CEMB + ks * 32 + (quad << 3));
            acc[nt] = __builtin_amdgcn_mfma_f32_16x16x32_bf16(a, bfrag, acc[nt], 0, 0, 0);
        }
    }
#pragma unroll
    for (int nt = 0; nt < 12; nt++) {
        float bias = proj_b[nt * 16 + l16];
#pragma unroll
        for (int r = 0; r < 4; r++) {
            int m = mt * 16 + (quad << 2) + r;
            out[(size_t)m * CEMB + nt * 16 + l16] = acc[nt][r] + bias;
        }
    }
}

// ---------------- launch ----------------
extern "C" void kernel_launch(void* const* d_in, const int* in_sizes, int n_in,
                              void* d_out, int out_size, void* d_ws, size_t ws_size,
                              hipStream_t stream) {
    (void)in_sizes; (void)n_in; (void)out_size; (void)ws_size;
    const float* x_in    = (const float*)d_in[0];
    const float* x_cross = (const float*)d_in[1];
    const float* mask    = (const float*)d_in[2];
    const float* q_w     = (const float*)d_in[3];
    const float* kv_w    = (const float*)d_in[4];
    const float* proj_w  = (const float*)d_in[5];
    const float* proj_b  = (const float*)d_in[6];
    const float* btab    = (const float*)d_in[7];
    const int*   rel     = (const int*)d_in[8];
    float* out = (float*)d_out;
    char* ws = (char*)d_ws;

    // ws layout (bytes), total 155,955,200:
    unsigned short* qwb   = (unsigned short*)(ws + 0);           //     73,728
    unsigned short* kvwb  = (unsigned short*)(ws + 73728);       //    147,456
    unsigned short* pwb   = (unsigned short*)(ws + 221184);      //     73,728
    unsigned short* biasT = (unsigned short*)(ws + 294912);      //  1,486,848
    unsigned short* maskT = (unsigned short*)(ws + 1781760);     // 15,859,712
    unsigned short* attnb = (unsigned short*)(ws + 17641472);    // 33,718,272
    unsigned short* Qb    = (unsigned short*)(ws + 51359744);    // 34,603,008
    unsigned short* Kb    = (unsigned short*)(ws + 85962752);    // 34,603,008
    unsigned short* Vtb   = (unsigned short*)(ws + 120565760);   // 35,389,440

    prep_weights<<<576, 256, 0, stream>>>(q_w, kv_w, proj_w, qwb, kvwb, pwb);
    prep_biasT<<<121, 256, 0, stream>>>(btab, rel, biasT);
    prep_maskT<<<64 * 121, 256, 0, stream>>>(mask, maskT);
    qkv_kernel<<<NB * 3, 512, 0, stream>>>(x_in, x_cross, qwb, kvwb, Qb, Kb, Vtb);
    attn_kernel<<<NB * NH, 512, 63488, stream>>>(Qb, Kb, Vtb, biasT, maskT, attnb);
    proj_kernel<<<5488 / 4, 256, 0, stream>>>(attnb, pwb, proj_b, out);
}